// Round 8
// baseline (247.902 us; speedup 1.0000x reference)
//
#include <hip/hip_runtime.h>
#include <math.h>

#define NN 4096   // nodes
#define LOG2E 1.44269504088896340736f

using f32x4  = __attribute__((ext_vector_type(4))) float;
using bf16x4 = __attribute__((ext_vector_type(4))) __bf16;
using bf16x8 = __attribute__((ext_vector_type(8))) __bf16;

// exp2 in one v_exp_f32 (inputs are pre-scaled by log2e)
#if __has_builtin(__builtin_amdgcn_exp2f)
#define EXP2(x) __builtin_amdgcn_exp2f(x)
#else
#define EXP2(x) __expf((x) * 0.6931471805599453f)
#endif

// counted-vmcnt barrier (T4): keep next-tile DMA in flight across the barrier.
#define WAITVM4_BARRIER asm volatile("s_waitcnt vmcnt(4)\ns_barrier" ::: "memory")
#define WAITVM0_BARRIER asm volatile("s_waitcnt vmcnt(0)\ns_barrier" ::: "memory")

// ---------------- async global->LDS staging (16B, XOR-swizzled chunks) ----------------
// Row f of 64 bf16 = 8 chunks of 8; LDS slot s of row f holds global chunk s^(f&7).
template<int FH>
__device__ __forceinline__ void stage_tile(const __bf16* __restrict__ hgp,
                                           __bf16* dst, int tid) {
#pragma unroll
    for (int it = 0; it < FH / 32; it++) {
        int c = tid + it * 256;
        int f = c >> 3, sl = c & 7;
        int g = sl ^ (f & 7);
        __builtin_amdgcn_global_load_lds(
            (const __attribute__((address_space(1))) void*)(hgp + (size_t)f * NN + g * 8),
            (__attribute__((address_space(3))) void*)(dst + (size_t)c * 8), 16, 0, 0);
    }
}

__device__ __forceinline__ void stage_g(const __bf16* __restrict__ base, int ldk,
                                        __bf16* dst, int tid) {
#pragma unroll
    for (int it = 0; it < 2; it++) {
        int c = tid + it * 256;
        int f = c >> 3, sl = c & 7;
        int g = sl ^ (f & 7);
        __builtin_amdgcn_global_load_lds(
            (const __attribute__((address_space(1))) void*)(base + (size_t)f * ldk + g * 8),
            (__attribute__((address_space(3))) void*)(dst + (size_t)c * 8), 16, 0, 0);
    }
}

// ---------------- fused prep: prepack + cast + zeroing (pack_adj moved to gemm1) ----
// Block-range partition:
//   [0, 1024):       W_h -> Bt1[n][k], W_o -> Bt2[n][k], biasp, zero s1/s2 accums
//   [1024, 3072):    X -> bf16 cast (f32x4 per thread)
__global__ void prep_kernel(const float* __restrict__ W_h, const float* __restrict__ b_h,
                            const float* __restrict__ W_o,
                            __bf16* __restrict__ Bt1, float* __restrict__ biasp,
                            __bf16* __restrict__ Bt2,
                            const float* __restrict__ X, __bf16* __restrict__ Xb,
                            float* __restrict__ zeros) {
    const int b = blockIdx.x, t = threadIdx.x;
    if (b < 1024) {                               // prepack + zeroing
        int idx = b * 256 + t;                    // [0, 262144)
        {
            int n = idx >> 9, k = idx & 511;
            int h = n >> 7, f = n & 127;
            Bt1[idx] = (__bf16)W_h[(size_t)h * 512 * 128 + k * 128 + f];
        }
        if (idx < 64 * 512) {
            int n = idx >> 9, k = idx & 511;
            Bt2[idx] = (__bf16)W_o[k * 64 + n];
        }
        if (idx < 512) biasp[idx] = b_h[idx];
        if (idx < (10 * NN) / 4)                  // zero s1h/s2h/s1o/s2o (40960 f32)
            *(f32x4*)(zeros + (size_t)idx * 4) = (f32x4){0.f, 0.f, 0.f, 0.f};
    } else {                                      // cast X -> bf16
        int i = (b - 1024) * 256 + t;             // [0, 524288) x4 floats
        f32x4 v = *(const f32x4*)(X + (size_t)i * 4);
        bf16x4 o;
#pragma unroll
        for (int q = 0; q < 4; q++) o[q] = (__bf16)v[q];
        *(bf16x4*)(Xb + (size_t)i * 4) = o;
    }
}

// ---------------- fused bf16 MFMA GEMM (triple-buffer + counted vmcnt) -------------
// + CONCURRENT pack_adj (blockIdx.z==1): adj_bits is needed only by the NEXT
// kernel (attn), so packing the 64 MB adjacency matrix overlaps with the
// latency-bound GEMM (2 blocks/CU) instead of serializing in front of it.
__global__ __launch_bounds__(256) void gemm_fused_kernel(
    const __bf16* __restrict__ A, const __bf16* __restrict__ Bt,
    const float* __restrict__ bias,
    const float* __restrict__ a1, const float* __restrict__ a2,
    __bf16* __restrict__ Ht, float* __restrict__ s1, float* __restrict__ s2,
    const int* __restrict__ adj, unsigned long long* __restrict__ adj_bits,
    int M, int N, int K)
{
    __shared__ __attribute__((aligned(16))) __bf16 As[3][64 * 64];
    __shared__ __attribute__((aligned(16))) __bf16 Bs[3][64 * 64];
    const int tid = threadIdx.x, w = tid >> 6, l = tid & 63, o = l >> 4, rl = l & 15;
    if (blockIdx.z == 1) {                        // fused pack_adj lane
        int bid = blockIdx.y * gridDim.x + blockIdx.x;   // [0, 512)
        int wv = bid * 4 + w;                     // [0, 2048)
        for (int it = 0; it < 128; it++) {
            int gw = wv * 128 + it;               // [0, 262144) 64-int groups
            int v = adj[(size_t)gw * 64 + l];
            unsigned long long m = __ballot(v > 0);
            if (l == 0) adj_bits[gw] = m;
        }
        return;
    }
    const int bm = blockIdx.y * 64, bn = blockIdx.x * 64;
    f32x4 acc[4] = {};
    // prologue: stage tiles 0 and 1 (8 DMA instructions in flight)
    stage_g(A + (size_t)bm * K, K, &As[0][0], tid);
    stage_g(Bt + (size_t)bn * K, K, &Bs[0][0], tid);
    stage_g(A + (size_t)bm * K + 64, K, &As[1][0], tid);
    stage_g(Bt + (size_t)bn * K + 64, K, &Bs[1][0], tid);
    const int KB = K / 64;                        // 8
    int b = 0;
    for (int kb = 0; kb < KB; kb++) {
        if (kb + 1 < KB) { WAITVM4_BARRIER; }     // tile kb landed; kb+1 in flight
        else             { WAITVM0_BARRIER; }     // last tile: full drain
#pragma unroll
        for (int kt = 0; kt < 2; kt++) {
            int ra = w * 16 + rl;
            int cg = kt * 4 + o;
            bf16x8 af = *(const bf16x8*)(&As[b][(ra * 8 + (cg ^ (ra & 7))) * 8]);
#pragma unroll
            for (int nt = 0; nt < 4; nt++) {
                int rb = nt * 16 + rl;
                bf16x8 bfr = *(const bf16x8*)(&Bs[b][(rb * 8 + (cg ^ (rb & 7))) * 8]);
                acc[nt] = __builtin_amdgcn_mfma_f32_16x16x32_bf16(af, bfr, acc[nt], 0, 0, 0);
            }
        }
        // stage kb+2 into the buffer last read at compute(kb-1)
        if (kb + 2 < KB) {
            int b2 = b + 2; if (b2 >= 3) b2 -= 3;
            stage_g(A + (size_t)bm * K + (kb + 2) * 64, K, &As[b2][0], tid);
            stage_g(Bt + (size_t)bn * K + (kb + 2) * 64, K, &Bs[b2][0], tid);
        }
        if (++b == 3) b = 0;
    }
    // epilogue: bias, transposed bf16 store, s1/s2 row-dot partials
    const int head = bn >> 7;
    const int row_base = bm + w * 16 + o * 4;
    float p1[4] = {0.f, 0.f, 0.f, 0.f}, p2[4] = {0.f, 0.f, 0.f, 0.f};
#pragma unroll
    for (int nt = 0; nt < 4; nt++) {
        int col = bn + nt * 16 + rl;
        float bv = bias[col];
        float a1v = a1[col] * LOG2E, a2v = a2[col] * LOG2E;
        bf16x4 hv;
#pragma unroll
        for (int r4 = 0; r4 < 4; r4++) {
            float h = acc[nt][r4] + bv;
            hv[r4] = (__bf16)h;
            p1[r4] += h * a1v;
            p2[r4] += h * a2v;
        }
        *(bf16x4*)(Ht + (size_t)col * M + row_base) = hv;
    }
#pragma unroll
    for (int r4 = 0; r4 < 4; r4++)
#pragma unroll
        for (int off = 1; off < 16; off <<= 1) {
            p1[r4] += __shfl_xor(p1[r4], off, 64);
            p2[r4] += __shfl_xor(p2[r4], off, 64);
        }
    if (rl == 0)
#pragma unroll
        for (int r4 = 0; r4 < 4; r4++) {
            atomicAdd(&s1[(size_t)head * M + row_base + r4], p1[r4]);
            atomicAdd(&s2[(size_t)head * M + row_base + r4], p2[r4]);
        }
}

// ---------------- MFMA attention, SELF-CONSUME + in-wave PMATH/MFMA overlap ----------
// R5 structure (wave w owns m-tile w across ALL n-tiles, one barrier/iter).
// R7: PMATH for tile jl+1 overlapped with the MFMA cluster of tile jl.
// R8: setprio(1) wraps ONLY the MFMA cluster (R7 mistakenly held high priority
// through the wave's own PMATH VALU chain, defeating the arbitration hint).
template<int FH, int JSPLIT>
__global__ __launch_bounds__(256, 4) void attn_kernel(
    const __bf16* __restrict__ Htg,               // [heads*FH][NN]
    const unsigned long long* __restrict__ adj_bits,
    const float* __restrict__ s1_all, const float* __restrict__ s2_all,
    const float* __restrict__ ab_all,
    __bf16* __restrict__ accp,                    // [JSPLIT][NN][ldo]
    float* __restrict__ lg,                       // [heads*JSPLIT][NN]
    int ldo)
{
    constexpr int NJT = NN / 64 / JSPLIT;         // 16 (layer1) / 4 (layer2)
    constexpr int NTL = FH / 16;                  // n-tiles per wave (8 or 4)
    const int head = blockIdx.y;
    const int js   = blockIdx.z;
    const int row0 = blockIdx.x * 64;
    const int jt0  = js * NJT;
    const int tid = threadIdx.x;
    const int w = tid >> 6, l = tid & 63, o = l >> 4, rl = l & 15;
    const int myrow = row0 + w * 16 + rl;         // this wave's m-tile rows

    __shared__ __attribute__((aligned(16))) __bf16 hbuf[2][FH * 64];

    const float* s2 = s2_all + (size_t)head * NN;
    const __bf16* hg = Htg + (size_t)head * FH * NN;
    const float s1r = s1_all[(size_t)head * NN + myrow] + ab_all[head] * LOG2E;
    const float u0 = s1r;                         // e = max(s+u0, fma(.2,s,v0))
    const float v0 = 0.2f * s1r;
    float lacc = 0.f;                             // per-lane partial; reduced at end
    f32x4 acc[NTL] = {};                          // m-tile w, all n-tiles

    // ---- flat prefetch state (named regs only -> guaranteed VGPRs)
    unsigned long long aw;
    f32x4 sA0, sB0, sA1, sB1;                     // s2[jt*64 + kt*32 + o*8 ..+8)

    auto PLOAD = [&](int jt) {
        aw = adj_bits[(size_t)myrow * 64 + jt];
        const float* sp = s2 + jt * 64 + o * 8;
        sA0 = *(const f32x4*)(sp);       sB0 = *(const f32x4*)(sp + 4);
        sA1 = *(const f32x4*)(sp + 32);  sB1 = *(const f32x4*)(sp + 36);
    };
    auto PMATH = [&](bf16x8& f0, bf16x8& f1) {
        float ps = 0.f;
        {
            unsigned int mb = (unsigned int)(aw >> (o * 8)) & 0xFFu;      // kt=0
#pragma unroll
            for (int q = 0; q < 8; q++) {
                float s = (q < 4) ? sA0[q] : sB0[q - 4];
                float t = fmaxf(s + u0, fmaf(0.2f, s, v0));
                t = ((mb >> q) & 1u) ? t : -1.0e20f;
                float p = EXP2(t);
                f0[q] = (__bf16)p; ps += p;
            }
        }
        {
            unsigned int mb = (unsigned int)(aw >> (32 + o * 8)) & 0xFFu; // kt=1
#pragma unroll
            for (int q = 0; q < 8; q++) {
                float s = (q < 4) ? sA1[q] : sB1[q - 4];
                float t = fmaxf(s + u0, fmaf(0.2f, s, v0));
                t = ((mb >> q) & 1u) ? t : -1.0e20f;
                float p = EXP2(t);
                f1[q] = (__bf16)p; ps += p;
            }
        }
        lacc += ps;
    };

    stage_tile<FH>(hg + (size_t)jt0 * 64, &hbuf[0][0], tid);
    PLOAD(jt0);
    bf16x8 fc0, fc1, fn0, fn1;
    PMATH(fc0, fc1);                              // tile 0 fragments (overlaps DMA)
    if (NJT > 1) PLOAD(jt0 + 1);

    for (int jl = 0; jl < NJT; jl++) {
        const int b = jl & 1;
        const int jt = jt0 + jl;
        // ONE barrier: hbuf[b] DMA drained (vmcnt 0); hbuf[b^1] free to overwrite
        __syncthreads();
        if (jl + 1 < NJT)
            stage_tile<FH>(hg + (size_t)(jt + 1) * 64, &hbuf[b ^ 1][0], tid);
        // produce NEXT tile's fragments (independent of fc / hbuf[b]) — the
        // scheduler interleaves this VALU chain with the MFMA cluster below.
        if (jl + 1 < NJT) PMATH(fn0, fn1);
        if (jl + 2 < NJT) PLOAD(jt + 2);
        // consume: own m-tile, ALL n-tiles (wave-local, no cross-wave sync)
        __builtin_amdgcn_s_setprio(1);
#pragma unroll
        for (int ntl = 0; ntl < NTL; ntl++) {
            int f = ntl * 16 + rl;
            int s0 = o ^ (rl & 7);                // kt=0 slot
            int s1 = (4 + o) ^ (rl & 7);          // kt=1 slot
            bf16x8 b0 = *(const bf16x8*)(&hbuf[b][(f * 8 + s0) * 8]);
            bf16x8 b1 = *(const bf16x8*)(&hbuf[b][(f * 8 + s1) * 8]);
            acc[ntl] = __builtin_amdgcn_mfma_f32_16x16x32_bf16(fc0, b0, acc[ntl], 0, 0, 0);
            acc[ntl] = __builtin_amdgcn_mfma_f32_16x16x32_bf16(fc1, b1, acc[ntl], 0, 0, 0);
        }
        __builtin_amdgcn_s_setprio(0);
        if (jl + 1 < NJT) { fc0 = fn0; fc1 = fn1; }
    }
    // ---- epilogue: cross-lane lacc reduce (deferred from loop) ----
    lacc += __shfl_xor(lacc, 16, 64);
    lacc += __shfl_xor(lacc, 32, 64);
    if (l < 16) lg[((size_t)head * JSPLIT + js) * NN + row0 + w * 16 + l] = lacc;
#pragma unroll
    for (int ntl = 0; ntl < NTL; ntl++)
#pragma unroll
        for (int r4 = 0; r4 < 4; r4++) {
            int grow = row0 + w * 16 + o * 4 + r4;
            int gcol = head * FH + ntl * 16 + rl;
            accp[((size_t)js * NN + grow) * ldo + gcol] = (__bf16)acc[ntl][r4];
        }
}

// ---------------- combine layer-1 partials: normalize + elu -> bf16 [N][512] ----------------
__global__ void combine1_kernel(const __bf16* __restrict__ accp, const float* __restrict__ lg,
                                __bf16* __restrict__ outb) {
    int gid = blockIdx.x * 256 + threadIdx.x;        // N * 128
    int row = gid >> 7, c4 = (gid & 127) * 4;
    int head = c4 >> 7;
    float lsum = 0.f;
#pragma unroll
    for (int js = 0; js < 4; js++) lsum += lg[((size_t)head * 4 + js) * NN + row];
    float inv = lsum > 0.f ? 1.f / lsum : 0.f;
    float v[4] = {0.f, 0.f, 0.f, 0.f};
#pragma unroll
    for (int js = 0; js < 4; js++) {
        bf16x4 t = *(const bf16x4*)(accp + ((size_t)js * NN + row) * 512 + c4);
#pragma unroll
        for (int q = 0; q < 4; q++) v[q] += (float)t[q];
    }
    bf16x4 ob;
#pragma unroll
    for (int q = 0; q < 4; q++) {
        float x = v[q] * inv;
        x = x > 0.f ? x : __expf(x) - 1.f;
        ob[q] = (__bf16)x;
    }
    *(bf16x4*)(outb + (size_t)row * 512 + c4) = ob;
}

// ---------------- combine layer-2 partials + elu + log_softmax -> out ----------------
__global__ void combine2_kernel(const __bf16* __restrict__ accp, const float* __restrict__ lg,
                                float* __restrict__ out) {
    int row = (blockIdx.x * 256 + threadIdx.x) >> 6;
    int lane = threadIdx.x & 63;
    if (row >= NN) return;
    float lsum = 0.f, v = 0.f;
#pragma unroll
    for (int js = 0; js < 16; js++) {
        lsum += lg[(size_t)js * NN + row];
        v += (float)accp[((size_t)js * NN + row) * 64 + lane];
    }
    float inv = lsum > 0.f ? 1.f / lsum : 0.f;
    v *= inv;
    v = v > 0.f ? v : __expf(v) - 1.f;
    float m = v;
#pragma unroll
    for (int off = 1; off < 64; off <<= 1) m = fmaxf(m, __shfl_xor(m, off, 64));
    float ex = __expf(v - m);
    float s = ex;
#pragma unroll
    for (int off = 1; off < 64; off <<= 1) s += __shfl_xor(s, off, 64);
    out[(size_t)row * 64 + lane] = v - m - __logf(s);
}

extern "C" void kernel_launch(void* const* d_in, const int* in_sizes, int n_in,
                              void* d_out, int out_size, void* d_ws, size_t ws_size,
                              hipStream_t stream) {
    const float* X    = (const float*)d_in[0];
    const int*   adj  = (const int*)d_in[1];
    const float* W_h  = (const float*)d_in[2];
    const float* b_h  = (const float*)d_in[3];
    const float* a1_h = (const float*)d_in[4];
    const float* a2_h = (const float*)d_in[5];
    const float* ab_h = (const float*)d_in[6];
    const float* W_o  = (const float*)d_in[7];
    const float* b_o  = (const float*)d_in[8];
    const float* a1_o = (const float*)d_in[9];
    const float* a2_o = (const float*)d_in[10];
    const float* ab_o = (const float*)d_in[11];
    float* out = (float*)d_out;

    char* ws = (char*)d_ws;
    auto alloc = [&](size_t bytes) {
        char* p = ws; ws += (bytes + 255) & ~(size_t)255; return p;
    };
    unsigned long long* adj_bits = (unsigned long long*)alloc((size_t)NN * 64 * 8); // 2 MB
    __bf16* Bt1    = (__bf16*)alloc((size_t)512 * 512 * 2);     // 512 KB
    float*  biasp  = (float*)alloc(512 * 4);
    __bf16* Bt2    = (__bf16*)alloc((size_t)64 * 512 * 2);      // 64 KB
    __bf16* Xb     = (__bf16*)alloc((size_t)NN * 512 * 2);      // 4 MB
    float*  s1h    = (float*)alloc((size_t)4 * NN * 4);         // |-- contiguous,
    float*  s2h    = (float*)alloc((size_t)4 * NN * 4);         // |   zeroed by prep
    float*  s1o    = (float*)alloc((size_t)NN * 4);             // |   (160 KB)
    float*  s2o    = (float*)alloc((size_t)NN * 4);             // |
    __bf16* Htg    = (__bf16*)alloc((size_t)512 * NN * 2);      // 4 MB
    __bf16* accp1  = (__bf16*)alloc((size_t)4 * NN * 512 * 2);  // 16 MB
    float*  lg1    = (float*)alloc((size_t)16 * NN * 4);        // 256 KB
    __bf16* outhb  = (__bf16*)alloc((size_t)NN * 512 * 2);      // 4 MB
    __bf16* Ht2    = (__bf16*)alloc((size_t)64 * NN * 2);       // 512 KB
    __bf16* accp2  = (__bf16*)alloc((size_t)16 * NN * 64 * 2);  // 8 MB
    float*  lg2    = (float*)alloc((size_t)16 * NN * 4);        // 256 KB  (~40 MB)

    // 1. prep: weight prepack, X cast, s1/s2 zeroing (pack_adj moved into gemm1)
    prep_kernel<<<3072, 256, 0, stream>>>(W_h, b_h, W_o, Bt1, biasp, Bt2, X, Xb, s1h);
    // 2. layer-1 GEMM fused + CONCURRENT adjacency packing (z==1 blocks).
    //    adj_bits is consumed first by attn1 (next dispatch) — dependency safe.
    gemm_fused_kernel<<<dim3(8, 64, 2), 256, 0, stream>>>(
        Xb, Bt1, biasp, a1_h, a2_h, Htg, s1h, s2h, adj, adj_bits, NN, 512, 512);
    // 3. attention layer 1 partials (4 heads x 4 j-splits)
    attn_kernel<128, 4><<<dim3(NN / 64, 4, 4), 256, 0, stream>>>(
        Htg, adj_bits, s1h, s2h, ab_h, accp1, lg1, 512);
    // 4. combine -> elu -> bf16 concat features [N][512]
    combine1_kernel<<<(NN * 128) / 256, 256, 0, stream>>>(accp1, lg1, outhb);
    // 5. layer-2 GEMM fused (no pack lane: z extent 1, adj ignored)
    gemm_fused_kernel<<<dim3(1, 64, 1), 256, 0, stream>>>(
        outhb, Bt2, b_o, a1_o, a2_o, Ht2, s1o, s2o, adj, adj_bits, NN, 64, 512);
    // 6. attention layer 2 partials (16 j-splits)
    attn_kernel<64, 16><<<dim3(NN / 64, 1, 16), 256, 0, stream>>>(
        Ht2, adj_bits, s1o, s2o, ab_o, accp2, lg2, 64);
    // 7. combine + elu + log_softmax -> out
    combine2_kernel<<<(NN * 64) / 256, 256, 0, stream>>>(accp2, lg2, out);
}

// Round 9
// 205.292 us; speedup vs baseline: 1.2076x; 1.2076x over previous
//
#include <hip/hip_runtime.h>
#include <math.h>

#define NN 4096   // nodes
#define LOG2E 1.44269504088896340736f

using f32x4  = __attribute__((ext_vector_type(4))) float;
using bf16x4 = __attribute__((ext_vector_type(4))) __bf16;
using bf16x8 = __attribute__((ext_vector_type(8))) __bf16;

// exp2 in one v_exp_f32 (inputs are pre-scaled by log2e)
#if __has_builtin(__builtin_amdgcn_exp2f)
#define EXP2(x) __builtin_amdgcn_exp2f(x)
#else
#define EXP2(x) __expf((x) * 0.6931471805599453f)
#endif

// counted-vmcnt barrier (T4): keep next-tile DMA in flight across the barrier.
#define WAITVM4_BARRIER asm volatile("s_waitcnt vmcnt(4)\ns_barrier" ::: "memory")
#define WAITVM0_BARRIER asm volatile("s_waitcnt vmcnt(0)\ns_barrier" ::: "memory")

// ---------------- async global->LDS staging (16B, XOR-swizzled chunks) ----------------
// Row f of 64 bf16 = 8 chunks of 8; LDS slot s of row f holds global chunk s^(f&7).
template<int FH>
__device__ __forceinline__ void stage_tile(const __bf16* __restrict__ hgp,
                                           __bf16* dst, int tid) {
#pragma unroll
    for (int it = 0; it < FH / 32; it++) {
        int c = tid + it * 256;
        int f = c >> 3, sl = c & 7;
        int g = sl ^ (f & 7);
        __builtin_amdgcn_global_load_lds(
            (const __attribute__((address_space(1))) void*)(hgp + (size_t)f * NN + g * 8),
            (__attribute__((address_space(3))) void*)(dst + (size_t)c * 8), 16, 0, 0);
    }
}

__device__ __forceinline__ void stage_g(const __bf16* __restrict__ base, int ldk,
                                        __bf16* dst, int tid) {
#pragma unroll
    for (int it = 0; it < 2; it++) {
        int c = tid + it * 256;
        int f = c >> 3, sl = c & 7;
        int g = sl ^ (f & 7);
        __builtin_amdgcn_global_load_lds(
            (const __attribute__((address_space(1))) void*)(base + (size_t)f * ldk + g * 8),
            (__attribute__((address_space(3))) void*)(dst + (size_t)c * 8), 16, 0, 0);
    }
}

// ---------------- fused prep: memset + prepack + cast + pack_adj (R7 config) --------
// R8 lesson: pack_adj needs MASSIVE wave parallelism (it's a dependent
// load->ballot chain). 4096 blocks x 4 waves x 16 iters works; 512x4x128 died.
__global__ void prep_kernel(const int* __restrict__ adj, unsigned long long* __restrict__ bits,
                            const float* __restrict__ W_h, const float* __restrict__ b_h,
                            const float* __restrict__ W_o,
                            __bf16* __restrict__ Bt1, float* __restrict__ biasp,
                            __bf16* __restrict__ Bt2,
                            const float* __restrict__ X, __bf16* __restrict__ Xb,
                            float* __restrict__ zeros) {
    const int b = blockIdx.x, t = threadIdx.x;
    if (b < 1024) {                               // prepack + zeroing
        int idx = b * 256 + t;                    // [0, 262144)
        {
            int n = idx >> 9, k = idx & 511;
            int h = n >> 7, f = n & 127;
            Bt1[idx] = (__bf16)W_h[(size_t)h * 512 * 128 + k * 128 + f];
        }
        if (idx < 64 * 512) {
            int n = idx >> 9, k = idx & 511;
            Bt2[idx] = (__bf16)W_o[k * 64 + n];
        }
        if (idx < 512) biasp[idx] = b_h[idx];
        if (idx < (10 * NN) / 4)                  // zero s1h/s2h/s1o/s2o (40960 f32)
            *(f32x4*)(zeros + (size_t)idx * 4) = (f32x4){0.f, 0.f, 0.f, 0.f};
    } else if (b < 3072) {                        // cast X -> bf16
        int i = (b - 1024) * 256 + t;             // [0, 524288) x4 floats
        f32x4 v = *(const f32x4*)(X + (size_t)i * 4);
        bf16x4 o;
#pragma unroll
        for (int q = 0; q < 4; q++) o[q] = (__bf16)v[q];
        *(bf16x4*)(Xb + (size_t)i * 4) = o;
    } else {                                      // pack_adj, grid-strided
        int wave = (b - 3072) * 4 + (t >> 6);     // [0, 16384)
        int lane = t & 63;
        int g0 = wave * 16;                       // 16 consecutive 64-col groups
        for (int it = 0; it < 16; it++) {
            int gw = g0 + it;
            int v = adj[(size_t)gw * 64 + lane];
            unsigned long long m = __ballot(v > 0);
            if (lane == 0) bits[gw] = m;
        }
    }
}

// ---------------- fused bf16 MFMA GEMM ----------------
// FUSEA=0 (layer 1): A staged via global_load_lds, triple-buffer + counted vmcnt.
// FUSEA=1 (layer 2): A = combine1 fused inline — A[row][col] =
//   elu( (sum_js accp1[js][row][col]) * inv[row, head(col)] ), reg-staged with
//   ds_write into the same XOR-swizzled layout. N=64 so A is read exactly once:
//   the fusion duplicates no work and deletes the combine1 dispatch + the
//   outhb round-trip (4 MB write + 4 MB read). Double-buffer + __syncthreads
//   (vmcnt counting isn't clean with mixed reg-loads; 64 blocks, latency-bound).
template<int FUSEA>
__global__ __launch_bounds__(256) void gemm_fused_kernel(
    const __bf16* __restrict__ A, const __bf16* __restrict__ Bt,
    const float* __restrict__ bias,
    const float* __restrict__ a1, const float* __restrict__ a2,
    __bf16* __restrict__ Ht, float* __restrict__ s1, float* __restrict__ s2,
    const __bf16* __restrict__ accp, const float* __restrict__ lgin,
    int M, int N, int K)
{
    constexpr int NB = FUSEA ? 2 : 3;
    __shared__ __attribute__((aligned(16))) __bf16 As[NB][64 * 64];
    __shared__ __attribute__((aligned(16))) __bf16 Bs[NB][64 * 64];
    __shared__ float sinv[4][64];                 // FUSEA: 1/lsum per (head, row)
    const int tid = threadIdx.x, w = tid >> 6, l = tid & 63, o = l >> 4, rl = l & 15;
    const int bm = blockIdx.y * 64, bn = blockIdx.x * 64;
    f32x4 acc[4] = {};
    const int KB = K / 64;

    // FUSEA A-staging: load 4 js-slices of accp1, combine (same op order as the
    // old combine1 kernel -> bitwise-identical), elu, bf16, swizzled ds_write.
    auto stageA_fused = [&](int kb, __bf16* dst) {
#pragma unroll
        for (int it = 0; it < 2; it++) {
            int c = tid + it * 256;
            int f = c >> 3, sl = c & 7;
            int row = bm + f;
            int col = kb * 64 + sl * 8;
            float inv = sinv[kb >> 1][f];
            float vs[8] = {0.f, 0.f, 0.f, 0.f, 0.f, 0.f, 0.f, 0.f};
#pragma unroll
            for (int js = 0; js < 4; js++) {
                bf16x8 t = *(const bf16x8*)(accp + ((size_t)js * NN + row) * 512 + col);
#pragma unroll
                for (int q = 0; q < 8; q++) vs[q] += (float)t[q];
            }
            bf16x8 ob;
#pragma unroll
            for (int q = 0; q < 8; q++) {
                float x = vs[q] * inv;
                x = x > 0.f ? x : __expf(x) - 1.f;
                ob[q] = (__bf16)x;
            }
            *(bf16x8*)(dst + ((size_t)f * 8 + (sl ^ (f & 7))) * 8) = ob;
        }
    };

    if constexpr (FUSEA) {
        {   // per-block inv table: head = tid>>6, row = tid&63
            int h = tid >> 6, r = tid & 63;
            float ls = 0.f;
#pragma unroll
            for (int js = 0; js < 4; js++) ls += lgin[((size_t)(h * 4 + js)) * NN + bm + r];
            sinv[h][r] = ls > 0.f ? 1.f / ls : 0.f;
        }
        __syncthreads();                          // sinv visible
        stageA_fused(0, &As[0][0]);
        stage_g(Bt + (size_t)bn * K, K, &Bs[0][0], tid);
        for (int kb = 0; kb < KB; kb++) {
            int b = kb & 1;
            __syncthreads();                      // As[b]/Bs[b] ready
            if (kb + 1 < KB) {
                stageA_fused(kb + 1, &As[b ^ 1][0]);
                stage_g(Bt + (size_t)bn * K + (kb + 1) * 64, K, &Bs[b ^ 1][0], tid);
            }
#pragma unroll
            for (int kt = 0; kt < 2; kt++) {
                int ra = w * 16 + rl;
                int cg = kt * 4 + o;
                bf16x8 af = *(const bf16x8*)(&As[b][(ra * 8 + (cg ^ (ra & 7))) * 8]);
#pragma unroll
                for (int nt = 0; nt < 4; nt++) {
                    int rb = nt * 16 + rl;
                    bf16x8 bfr = *(const bf16x8*)(&Bs[b][(rb * 8 + (cg ^ (rb & 7))) * 8]);
                    acc[nt] = __builtin_amdgcn_mfma_f32_16x16x32_bf16(af, bfr, acc[nt], 0, 0, 0);
                }
            }
        }
    } else {
        // prologue: stage tiles 0 and 1 (8 DMA instructions in flight)
        stage_g(A + (size_t)bm * K, K, &As[0][0], tid);
        stage_g(Bt + (size_t)bn * K, K, &Bs[0][0], tid);
        stage_g(A + (size_t)bm * K + 64, K, &As[1][0], tid);
        stage_g(Bt + (size_t)bn * K + 64, K, &Bs[1][0], tid);
        int b = 0;
        for (int kb = 0; kb < KB; kb++) {
            if (kb + 1 < KB) { WAITVM4_BARRIER; } // tile kb landed; kb+1 in flight
            else             { WAITVM0_BARRIER; } // last tile: full drain
#pragma unroll
            for (int kt = 0; kt < 2; kt++) {
                int ra = w * 16 + rl;
                int cg = kt * 4 + o;
                bf16x8 af = *(const bf16x8*)(&As[b][(ra * 8 + (cg ^ (ra & 7))) * 8]);
#pragma unroll
                for (int nt = 0; nt < 4; nt++) {
                    int rb = nt * 16 + rl;
                    bf16x8 bfr = *(const bf16x8*)(&Bs[b][(rb * 8 + (cg ^ (rb & 7))) * 8]);
                    acc[nt] = __builtin_amdgcn_mfma_f32_16x16x32_bf16(af, bfr, acc[nt], 0, 0, 0);
                }
            }
            if (kb + 2 < KB) {                    // stage kb+2 (buffer free by now)
                int b2 = b + 2; if (b2 >= 3) b2 -= 3;
                stage_g(A + (size_t)bm * K + (kb + 2) * 64, K, &As[b2][0], tid);
                stage_g(Bt + (size_t)bn * K + (kb + 2) * 64, K, &Bs[b2][0], tid);
            }
            if (++b == 3) b = 0;
        }
    }
    // epilogue: bias, transposed bf16 store, s1/s2 row-dot partials
    const int head = bn >> 7;
    const int row_base = bm + w * 16 + o * 4;
    float p1[4] = {0.f, 0.f, 0.f, 0.f}, p2[4] = {0.f, 0.f, 0.f, 0.f};
#pragma unroll
    for (int nt = 0; nt < 4; nt++) {
        int col = bn + nt * 16 + rl;
        float bv = bias[col];
        float a1v = a1[col] * LOG2E, a2v = a2[col] * LOG2E;
        bf16x4 hv;
#pragma unroll
        for (int r4 = 0; r4 < 4; r4++) {
            float h = acc[nt][r4] + bv;
            hv[r4] = (__bf16)h;
            p1[r4] += h * a1v;
            p2[r4] += h * a2v;
        }
        *(bf16x4*)(Ht + (size_t)col * M + row_base) = hv;
    }
#pragma unroll
    for (int r4 = 0; r4 < 4; r4++)
#pragma unroll
        for (int off = 1; off < 16; off <<= 1) {
            p1[r4] += __shfl_xor(p1[r4], off, 64);
            p2[r4] += __shfl_xor(p2[r4], off, 64);
        }
    if (rl == 0)
#pragma unroll
        for (int r4 = 0; r4 < 4; r4++) {
            atomicAdd(&s1[(size_t)head * M + row_base + r4], p1[r4]);
            atomicAdd(&s2[(size_t)head * M + row_base + r4], p2[r4]);
        }
}

// ---------------- MFMA attention, SELF-CONSUME + in-wave PMATH/MFMA overlap ----------
// R5 structure; R7 PMATH pipelining; R8 setprio placement (MFMA cluster only).
template<int FH, int JSPLIT>
__global__ __launch_bounds__(256, 4) void attn_kernel(
    const __bf16* __restrict__ Htg,               // [heads*FH][NN]
    const unsigned long long* __restrict__ adj_bits,
    const float* __restrict__ s1_all, const float* __restrict__ s2_all,
    const float* __restrict__ ab_all,
    __bf16* __restrict__ accp,                    // [JSPLIT][NN][ldo]
    float* __restrict__ lg,                       // [heads*JSPLIT][NN]
    int ldo)
{
    constexpr int NJT = NN / 64 / JSPLIT;         // 16 (layer1) / 4 (layer2)
    constexpr int NTL = FH / 16;                  // n-tiles per wave (8 or 4)
    const int head = blockIdx.y;
    const int js   = blockIdx.z;
    const int row0 = blockIdx.x * 64;
    const int jt0  = js * NJT;
    const int tid = threadIdx.x;
    const int w = tid >> 6, l = tid & 63, o = l >> 4, rl = l & 15;
    const int myrow = row0 + w * 16 + rl;         // this wave's m-tile rows

    __shared__ __attribute__((aligned(16))) __bf16 hbuf[2][FH * 64];

    const float* s2 = s2_all + (size_t)head * NN;
    const __bf16* hg = Htg + (size_t)head * FH * NN;
    const float s1r = s1_all[(size_t)head * NN + myrow] + ab_all[head] * LOG2E;
    const float u0 = s1r;                         // e = max(s+u0, fma(.2,s,v0))
    const float v0 = 0.2f * s1r;
    float lacc = 0.f;                             // per-lane partial; reduced at end
    f32x4 acc[NTL] = {};                          // m-tile w, all n-tiles

    // ---- flat prefetch state (named regs only -> guaranteed VGPRs)
    unsigned long long aw;
    f32x4 sA0, sB0, sA1, sB1;                     // s2[jt*64 + kt*32 + o*8 ..+8)

    auto PLOAD = [&](int jt) {
        aw = adj_bits[(size_t)myrow * 64 + jt];
        const float* sp = s2 + jt * 64 + o * 8;
        sA0 = *(const f32x4*)(sp);       sB0 = *(const f32x4*)(sp + 4);
        sA1 = *(const f32x4*)(sp + 32);  sB1 = *(const f32x4*)(sp + 36);
    };
    auto PMATH = [&](bf16x8& f0, bf16x8& f1) {
        float ps = 0.f;
        {
            unsigned int mb = (unsigned int)(aw >> (o * 8)) & 0xFFu;      // kt=0
#pragma unroll
            for (int q = 0; q < 8; q++) {
                float s = (q < 4) ? sA0[q] : sB0[q - 4];
                float t = fmaxf(s + u0, fmaf(0.2f, s, v0));
                t = ((mb >> q) & 1u) ? t : -1.0e20f;
                float p = EXP2(t);
                f0[q] = (__bf16)p; ps += p;
            }
        }
        {
            unsigned int mb = (unsigned int)(aw >> (32 + o * 8)) & 0xFFu; // kt=1
#pragma unroll
            for (int q = 0; q < 8; q++) {
                float s = (q < 4) ? sA1[q] : sB1[q - 4];
                float t = fmaxf(s + u0, fmaf(0.2f, s, v0));
                t = ((mb >> q) & 1u) ? t : -1.0e20f;
                float p = EXP2(t);
                f1[q] = (__bf16)p; ps += p;
            }
        }
        lacc += ps;
    };

    stage_tile<FH>(hg + (size_t)jt0 * 64, &hbuf[0][0], tid);
    PLOAD(jt0);
    bf16x8 fc0, fc1, fn0, fn1;
    PMATH(fc0, fc1);                              // tile 0 fragments (overlaps DMA)
    if (NJT > 1) PLOAD(jt0 + 1);

    for (int jl = 0; jl < NJT; jl++) {
        const int b = jl & 1;
        const int jt = jt0 + jl;
        // ONE barrier: hbuf[b] DMA drained (vmcnt 0); hbuf[b^1] free to overwrite
        __syncthreads();
        if (jl + 1 < NJT)
            stage_tile<FH>(hg + (size_t)(jt + 1) * 64, &hbuf[b ^ 1][0], tid);
        // produce NEXT tile's fragments (independent of fc / hbuf[b]) — the
        // scheduler interleaves this VALU chain with the MFMA cluster below.
        if (jl + 1 < NJT) PMATH(fn0, fn1);
        if (jl + 2 < NJT) PLOAD(jt + 2);
        // consume: own m-tile, ALL n-tiles (wave-local, no cross-wave sync)
        __builtin_amdgcn_s_setprio(1);
#pragma unroll
        for (int ntl = 0; ntl < NTL; ntl++) {
            int f = ntl * 16 + rl;
            int s0 = o ^ (rl & 7);                // kt=0 slot
            int s1 = (4 + o) ^ (rl & 7);          // kt=1 slot
            bf16x8 b0 = *(const bf16x8*)(&hbuf[b][(f * 8 + s0) * 8]);
            bf16x8 b1 = *(const bf16x8*)(&hbuf[b][(f * 8 + s1) * 8]);
            acc[ntl] = __builtin_amdgcn_mfma_f32_16x16x32_bf16(fc0, b0, acc[ntl], 0, 0, 0);
            acc[ntl] = __builtin_amdgcn_mfma_f32_16x16x32_bf16(fc1, b1, acc[ntl], 0, 0, 0);
        }
        __builtin_amdgcn_s_setprio(0);
        if (jl + 1 < NJT) { fc0 = fn0; fc1 = fn1; }
    }
    // ---- epilogue: cross-lane lacc reduce (deferred from loop) ----
    lacc += __shfl_xor(lacc, 16, 64);
    lacc += __shfl_xor(lacc, 32, 64);
    if (l < 16) lg[((size_t)head * JSPLIT + js) * NN + row0 + w * 16 + l] = lacc;
#pragma unroll
    for (int ntl = 0; ntl < NTL; ntl++)
#pragma unroll
        for (int r4 = 0; r4 < 4; r4++) {
            int grow = row0 + w * 16 + o * 4 + r4;
            int gcol = head * FH + ntl * 16 + rl;
            accp[((size_t)js * NN + grow) * ldo + gcol] = (__bf16)acc[ntl][r4];
        }
}

// ---------------- combine layer-2 partials + elu + log_softmax -> out ----------------
__global__ void combine2_kernel(const __bf16* __restrict__ accp, const float* __restrict__ lg,
                                float* __restrict__ out) {
    int row = (blockIdx.x * 256 + threadIdx.x) >> 6;
    int lane = threadIdx.x & 63;
    if (row >= NN) return;
    float lsum = 0.f, v = 0.f;
#pragma unroll
    for (int js = 0; js < 16; js++) {
        lsum += lg[(size_t)js * NN + row];
        v += (float)accp[((size_t)js * NN + row) * 64 + lane];
    }
    float inv = lsum > 0.f ? 1.f / lsum : 0.f;
    v *= inv;
    v = v > 0.f ? v : __expf(v) - 1.f;
    float m = v;
#pragma unroll
    for (int off = 1; off < 64; off <<= 1) m = fmaxf(m, __shfl_xor(m, off, 64));
    float ex = __expf(v - m);
    float s = ex;
#pragma unroll
    for (int off = 1; off < 64; off <<= 1) s += __shfl_xor(s, off, 64);
    out[(size_t)row * 64 + lane] = v - m - __logf(s);
}

extern "C" void kernel_launch(void* const* d_in, const int* in_sizes, int n_in,
                              void* d_out, int out_size, void* d_ws, size_t ws_size,
                              hipStream_t stream) {
    const float* X    = (const float*)d_in[0];
    const int*   adj  = (const int*)d_in[1];
    const float* W_h  = (const float*)d_in[2];
    const float* b_h  = (const float*)d_in[3];
    const float* a1_h = (const float*)d_in[4];
    const float* a2_h = (const float*)d_in[5];
    const float* ab_h = (const float*)d_in[6];
    const float* W_o  = (const float*)d_in[7];
    const float* b_o  = (const float*)d_in[8];
    const float* a1_o = (const float*)d_in[9];
    const float* a2_o = (const float*)d_in[10];
    const float* ab_o = (const float*)d_in[11];
    float* out = (float*)d_out;

    char* ws = (char*)d_ws;
    auto alloc = [&](size_t bytes) {
        char* p = ws; ws += (bytes + 255) & ~(size_t)255; return p;
    };
    unsigned long long* adj_bits = (unsigned long long*)alloc((size_t)NN * 64 * 8); // 2 MB
    __bf16* Bt1    = (__bf16*)alloc((size_t)512 * 512 * 2);     // 512 KB
    float*  biasp  = (float*)alloc(512 * 4);
    __bf16* Bt2    = (__bf16*)alloc((size_t)64 * 512 * 2);      // 64 KB
    __bf16* Xb     = (__bf16*)alloc((size_t)NN * 512 * 2);      // 4 MB
    float*  s1h    = (float*)alloc((size_t)4 * NN * 4);         // |-- contiguous,
    float*  s2h    = (float*)alloc((size_t)4 * NN * 4);         // |   zeroed by prep
    float*  s1o    = (float*)alloc((size_t)NN * 4);             // |   (160 KB)
    float*  s2o    = (float*)alloc((size_t)NN * 4);             // |
    __bf16* Htg    = (__bf16*)alloc((size_t)512 * NN * 2);      // 4 MB
    __bf16* accp1  = (__bf16*)alloc((size_t)4 * NN * 512 * 2);  // 16 MB
    float*  lg1    = (float*)alloc((size_t)16 * NN * 4);        // 256 KB
    __bf16* Ht2    = (__bf16*)alloc((size_t)64 * NN * 2);       // 512 KB
    __bf16* accp2  = (__bf16*)alloc((size_t)16 * NN * 64 * 2);  // 8 MB
    float*  lg2    = (float*)alloc((size_t)16 * NN * 4);        // 256 KB  (~36 MB)

    // 1. fused prep: adj->bits, weight prepack, X cast, s1/s2 zeroing (R7 config)
    prep_kernel<<<7168, 256, 0, stream>>>(adj, adj_bits, W_h, b_h, W_o,
                                          Bt1, biasp, Bt2, X, Xb, s1h);
    // 2. layer-1 GEMM fused: Htg (transposed bf16) + s1h/s2h atomics (LOG2E-scaled)
    gemm_fused_kernel<0><<<dim3(8, 64), 256, 0, stream>>>(
        Xb, Bt1, biasp, a1_h, a2_h, Htg, s1h, s2h, nullptr, nullptr, NN, 512, 512);
    // 3. attention layer 1 partials (4 heads x 4 j-splits)
    attn_kernel<128, 4><<<dim3(NN / 64, 4, 4), 256, 0, stream>>>(
        Htg, adj_bits, s1h, s2h, ab_h, accp1, lg1, 512);
    // 4. layer-2 GEMM with combine1 FUSED into the A-path (reads accp1+lg1 directly)
    gemm_fused_kernel<1><<<dim3(1, 64), 256, 0, stream>>>(
        nullptr, Bt2, b_o, a1_o, a2_o, Ht2, s1o, s2o, accp1, lg1, NN, 64, 512);
    // 5. attention layer 2 partials (16 j-splits)
    attn_kernel<64, 16><<<dim3(NN / 64, 1, 16), 256, 0, stream>>>(
        Ht2, adj_bits, s1o, s2o, ab_o, accp2, lg2, 64);
    // 6. combine + elu + log_softmax -> out
    combine2_kernel<<<(NN * 64) / 256, 256, 0, stream>>>(accp2, lg2, out);
}

// Round 10
// 199.114 us; speedup vs baseline: 1.2450x; 1.0310x over previous
//
#include <hip/hip_runtime.h>
#include <math.h>

#define NN 4096   // nodes
#define LOG2E 1.44269504088896340736f

using f32x4  = __attribute__((ext_vector_type(4))) float;
using bf16x4 = __attribute__((ext_vector_type(4))) __bf16;
using bf16x8 = __attribute__((ext_vector_type(8))) __bf16;

// exp2 in one v_exp_f32 (inputs are pre-scaled by log2e)
#if __has_builtin(__builtin_amdgcn_exp2f)
#define EXP2(x) __builtin_amdgcn_exp2f(x)
#else
#define EXP2(x) __expf((x) * 0.6931471805599453f)
#endif

// counted-vmcnt barrier (T4): keep next-tile DMA in flight across the barrier.
#define WAITVM4_BARRIER asm volatile("s_waitcnt vmcnt(4)\ns_barrier" ::: "memory")
#define WAITVM0_BARRIER asm volatile("s_waitcnt vmcnt(0)\ns_barrier" ::: "memory")

// ---------------- async global->LDS staging (16B, XOR-swizzled chunks) ----------------
// Row f of 64 bf16 = 8 chunks of 8; LDS slot s of row f holds global chunk s^(f&7).
template<int FH>
__device__ __forceinline__ void stage_tile(const __bf16* __restrict__ hgp,
                                           __bf16* dst, int tid) {
#pragma unroll
    for (int it = 0; it < FH / 32; it++) {
        int c = tid + it * 256;
        int f = c >> 3, sl = c & 7;
        int g = sl ^ (f & 7);
        __builtin_amdgcn_global_load_lds(
            (const __attribute__((address_space(1))) void*)(hgp + (size_t)f * NN + g * 8),
            (__attribute__((address_space(3))) void*)(dst + (size_t)c * 8), 16, 0, 0);
    }
}

__device__ __forceinline__ void stage_g(const __bf16* __restrict__ base, int ldk,
                                        __bf16* dst, int tid) {
#pragma unroll
    for (int it = 0; it < 2; it++) {
        int c = tid + it * 256;
        int f = c >> 3, sl = c & 7;
        int g = sl ^ (f & 7);
        __builtin_amdgcn_global_load_lds(
            (const __attribute__((address_space(1))) void*)(base + (size_t)f * ldk + g * 8),
            (__attribute__((address_space(3))) void*)(dst + (size_t)c * 8), 16, 0, 0);
    }
}

// ---------------- fused prep: memset + prepack + cast + pack_adj (R7 config) --------
// pack_adj needs MASSIVE wave parallelism (dependent load->ballot chain):
// 4096 blocks x 4 waves x 16 iters works; 512x4x128 died (R8).
__global__ void prep_kernel(const int* __restrict__ adj, unsigned long long* __restrict__ bits,
                            const float* __restrict__ W_h, const float* __restrict__ b_h,
                            const float* __restrict__ W_o,
                            __bf16* __restrict__ Bt1, float* __restrict__ biasp,
                            __bf16* __restrict__ Bt2,
                            const float* __restrict__ X, __bf16* __restrict__ Xb,
                            float* __restrict__ zeros) {
    const int b = blockIdx.x, t = threadIdx.x;
    if (b < 1024) {                               // prepack + zeroing
        int idx = b * 256 + t;                    // [0, 262144)
        {
            int n = idx >> 9, k = idx & 511;
            int h = n >> 7, f = n & 127;
            Bt1[idx] = (__bf16)W_h[(size_t)h * 512 * 128 + k * 128 + f];
        }
        if (idx < 64 * 512) {
            int n = idx >> 9, k = idx & 511;
            Bt2[idx] = (__bf16)W_o[k * 64 + n];
        }
        if (idx < 512) biasp[idx] = b_h[idx];
        if (idx < (10 * NN) / 4)                  // zero s1h/s2h/s1o/s2o (40960 f32)
            *(f32x4*)(zeros + (size_t)idx * 4) = (f32x4){0.f, 0.f, 0.f, 0.f};
    } else if (b < 3072) {                        // cast X -> bf16
        int i = (b - 1024) * 256 + t;             // [0, 524288) x4 floats
        f32x4 v = *(const f32x4*)(X + (size_t)i * 4);
        bf16x4 o;
#pragma unroll
        for (int q = 0; q < 4; q++) o[q] = (__bf16)v[q];
        *(bf16x4*)(Xb + (size_t)i * 4) = o;
    } else {                                      // pack_adj, grid-strided
        int wave = (b - 3072) * 4 + (t >> 6);     // [0, 16384)
        int lane = t & 63;
        int g0 = wave * 16;                       // 16 consecutive 64-col groups
        for (int it = 0; it < 16; it++) {
            int gw = g0 + it;
            int v = adj[(size_t)gw * 64 + lane];
            unsigned long long m = __ballot(v > 0);
            if (lane == 0) bits[gw] = m;
        }
    }
}

// ---------------- fused bf16 MFMA GEMM ----------------
// FUSEA=0 (layer 1): A staged via global_load_lds, triple-buffer + counted vmcnt.
// FUSEA=1 (layer 2): A = combine1 fused inline (N=64: A read exactly once).
template<int FUSEA>
__global__ __launch_bounds__(256) void gemm_fused_kernel(
    const __bf16* __restrict__ A, const __bf16* __restrict__ Bt,
    const float* __restrict__ bias,
    const float* __restrict__ a1, const float* __restrict__ a2,
    __bf16* __restrict__ Ht, float* __restrict__ s1, float* __restrict__ s2,
    const __bf16* __restrict__ accp, const float* __restrict__ lgin,
    int M, int N, int K)
{
    constexpr int NB = FUSEA ? 2 : 3;
    __shared__ __attribute__((aligned(16))) __bf16 As[NB][64 * 64];
    __shared__ __attribute__((aligned(16))) __bf16 Bs[NB][64 * 64];
    __shared__ float sinv[4][64];                 // FUSEA: 1/lsum per (head, row)
    const int tid = threadIdx.x, w = tid >> 6, l = tid & 63, o = l >> 4, rl = l & 15;
    const int bm = blockIdx.y * 64, bn = blockIdx.x * 64;
    f32x4 acc[4] = {};
    const int KB = K / 64;

    // FUSEA A-staging: load 4 js-slices of accp1, combine (same op order as the
    // old combine1 kernel -> bitwise-identical), elu, bf16, swizzled ds_write.
    auto stageA_fused = [&](int kb, __bf16* dst) {
#pragma unroll
        for (int it = 0; it < 2; it++) {
            int c = tid + it * 256;
            int f = c >> 3, sl = c & 7;
            int row = bm + f;
            int col = kb * 64 + sl * 8;
            float inv = sinv[kb >> 1][f];
            float vs[8] = {0.f, 0.f, 0.f, 0.f, 0.f, 0.f, 0.f, 0.f};
#pragma unroll
            for (int js = 0; js < 4; js++) {
                bf16x8 t = *(const bf16x8*)(accp + ((size_t)js * NN + row) * 512 + col);
#pragma unroll
                for (int q = 0; q < 8; q++) vs[q] += (float)t[q];
            }
            bf16x8 ob;
#pragma unroll
            for (int q = 0; q < 8; q++) {
                float x = vs[q] * inv;
                x = x > 0.f ? x : __expf(x) - 1.f;
                ob[q] = (__bf16)x;
            }
            *(bf16x8*)(dst + ((size_t)f * 8 + (sl ^ (f & 7))) * 8) = ob;
        }
    };

    if constexpr (FUSEA) {
        {   // per-block inv table: head = tid>>6, row = tid&63
            int h = tid >> 6, r = tid & 63;
            float ls = 0.f;
#pragma unroll
            for (int js = 0; js < 4; js++) ls += lgin[((size_t)(h * 4 + js)) * NN + bm + r];
            sinv[h][r] = ls > 0.f ? 1.f / ls : 0.f;
        }
        __syncthreads();                          // sinv visible
        stageA_fused(0, &As[0][0]);
        stage_g(Bt + (size_t)bn * K, K, &Bs[0][0], tid);
        for (int kb = 0; kb < KB; kb++) {
            int b = kb & 1;
            __syncthreads();                      // As[b]/Bs[b] ready
            if (kb + 1 < KB) {
                stageA_fused(kb + 1, &As[b ^ 1][0]);
                stage_g(Bt + (size_t)bn * K + (kb + 1) * 64, K, &Bs[b ^ 1][0], tid);
            }
#pragma unroll
            for (int kt = 0; kt < 2; kt++) {
                int ra = w * 16 + rl;
                int cg = kt * 4 + o;
                bf16x8 af = *(const bf16x8*)(&As[b][(ra * 8 + (cg ^ (ra & 7))) * 8]);
#pragma unroll
                for (int nt = 0; nt < 4; nt++) {
                    int rb = nt * 16 + rl;
                    bf16x8 bfr = *(const bf16x8*)(&Bs[b][(rb * 8 + (cg ^ (rb & 7))) * 8]);
                    acc[nt] = __builtin_amdgcn_mfma_f32_16x16x32_bf16(af, bfr, acc[nt], 0, 0, 0);
                }
            }
        }
    } else {
        // prologue: stage tiles 0 and 1 (8 DMA instructions in flight)
        stage_g(A + (size_t)bm * K, K, &As[0][0], tid);
        stage_g(Bt + (size_t)bn * K, K, &Bs[0][0], tid);
        stage_g(A + (size_t)bm * K + 64, K, &As[1][0], tid);
        stage_g(Bt + (size_t)bn * K + 64, K, &Bs[1][0], tid);
        int b = 0;
        for (int kb = 0; kb < KB; kb++) {
            if (kb + 1 < KB) { WAITVM4_BARRIER; } // tile kb landed; kb+1 in flight
            else             { WAITVM0_BARRIER; } // last tile: full drain
#pragma unroll
            for (int kt = 0; kt < 2; kt++) {
                int ra = w * 16 + rl;
                int cg = kt * 4 + o;
                bf16x8 af = *(const bf16x8*)(&As[b][(ra * 8 + (cg ^ (ra & 7))) * 8]);
#pragma unroll
                for (int nt = 0; nt < 4; nt++) {
                    int rb = nt * 16 + rl;
                    bf16x8 bfr = *(const bf16x8*)(&Bs[b][(rb * 8 + (cg ^ (rb & 7))) * 8]);
                    acc[nt] = __builtin_amdgcn_mfma_f32_16x16x32_bf16(af, bfr, acc[nt], 0, 0, 0);
                }
            }
            if (kb + 2 < KB) {                    // stage kb+2 (buffer free by now)
                int b2 = b + 2; if (b2 >= 3) b2 -= 3;
                stage_g(A + (size_t)bm * K + (kb + 2) * 64, K, &As[b2][0], tid);
                stage_g(Bt + (size_t)bn * K + (kb + 2) * 64, K, &Bs[b2][0], tid);
            }
            if (++b == 3) b = 0;
        }
    }
    // epilogue: bias, transposed bf16 store, s1/s2 row-dot partials
    const int head = bn >> 7;
    const int row_base = bm + w * 16 + o * 4;
    float p1[4] = {0.f, 0.f, 0.f, 0.f}, p2[4] = {0.f, 0.f, 0.f, 0.f};
#pragma unroll
    for (int nt = 0; nt < 4; nt++) {
        int col = bn + nt * 16 + rl;
        float bv = bias[col];
        float a1v = a1[col] * LOG2E, a2v = a2[col] * LOG2E;
        bf16x4 hv;
#pragma unroll
        for (int r4 = 0; r4 < 4; r4++) {
            float h = acc[nt][r4] + bv;
            hv[r4] = (__bf16)h;
            p1[r4] += h * a1v;
            p2[r4] += h * a2v;
        }
        *(bf16x4*)(Ht + (size_t)col * M + row_base) = hv;
    }
#pragma unroll
    for (int r4 = 0; r4 < 4; r4++)
#pragma unroll
        for (int off = 1; off < 16; off <<= 1) {
            p1[r4] += __shfl_xor(p1[r4], off, 64);
            p2[r4] += __shfl_xor(p2[r4], off, 64);
        }
    if (rl == 0)
#pragma unroll
        for (int r4 = 0; r4 < 4; r4++) {
            atomicAdd(&s1[(size_t)head * M + row_base + r4], p1[r4]);
            atomicAdd(&s2[(size_t)head * M + row_base + r4], p2[r4]);
        }
}

// ---------------- MFMA attention, SELF-CONSUME + E-factorized softmax ----------------
// R5 structure; R7 PMATH pipelining; R8 setprio placement.
// Round-10: exp REMOVED from the inner loop. Since exp2 is monotone,
//   exp2(lrelu(s1+s2)) = max(exp2(s1)·exp2(s2), exp2(0.2·s1)·exp2(0.2·s2)).
// E1[j]=exp2(s2j), E2[j]=exp2(0.2·s2j) are computed ONCE per block into LDS
// (NJT*64 j's, ~8 exp2/lane, prologue); F1/F2 once per row. Inner loop per
// element: 2 mul + max + cndmask (was add+fma+max+cndmask+exp). E reads are
// 4-distinct-address broadcast ds_reads (conflict-free). PLOAD shrinks to the
// adjacency word alone.
template<int FH, int JSPLIT>
__global__ __launch_bounds__(256, 4) void attn_kernel(
    const __bf16* __restrict__ Htg,               // [heads*FH][NN]
    const unsigned long long* __restrict__ adj_bits,
    const float* __restrict__ s1_all, const float* __restrict__ s2_all,
    const float* __restrict__ ab_all,
    __bf16* __restrict__ accp,                    // [JSPLIT][NN][ldo]
    float* __restrict__ lg,                       // [heads*JSPLIT][NN]
    int ldo)
{
    constexpr int NJT = NN / 64 / JSPLIT;         // 16 (layer1) / 4 (layer2)
    constexpr int NTL = FH / 16;                  // n-tiles per wave (8 or 4)
    const int head = blockIdx.y;
    const int js   = blockIdx.z;
    const int row0 = blockIdx.x * 64;
    const int jt0  = js * NJT;
    const int tid = threadIdx.x;
    const int w = tid >> 6, l = tid & 63, o = l >> 4, rl = l & 15;
    const int myrow = row0 + w * 16 + rl;         // this wave's m-tile rows

    __shared__ __attribute__((aligned(16))) __bf16 hbuf[2][FH * 64];
    __shared__ __attribute__((aligned(16))) float el1[NJT * 64];
    __shared__ __attribute__((aligned(16))) float el2[NJT * 64];

    const float* s2 = s2_all + (size_t)head * NN;
    const __bf16* hg = Htg + (size_t)head * FH * NN;
    const float s1r = s1_all[(size_t)head * NN + myrow] + ab_all[head] * LOG2E;
    const float F1 = EXP2(s1r);                   // exp2 of row term
    const float F2 = EXP2(0.2f * s1r);            // exp2 of 0.2*row term
    float lacc = 0.f;                             // per-lane partial; reduced at end
    f32x4 acc[NTL] = {};                          // m-tile w, all n-tiles

    unsigned long long aw;                        // adjacency word (prefetched)
    auto PLOAD = [&](int jt) { aw = adj_bits[(size_t)myrow * 64 + jt]; };
    // PMATH reads E1/E2 from LDS at block-local tile index jl.
    auto PMATH = [&](int jl, bf16x8& f0, bf16x8& f1) {
        float ps = 0.f;
#pragma unroll
        for (int kt = 0; kt < 2; kt++) {
            unsigned int mb = (unsigned int)(aw >> ((kt * 4 + o) * 8)) & 0xFFu;
            int eb = jl * 64 + kt * 32 + o * 8;
            f32x4 e1a = *(const f32x4*)(&el1[eb]);
            f32x4 e1b = *(const f32x4*)(&el1[eb + 4]);
            f32x4 e2a = *(const f32x4*)(&el2[eb]);
            f32x4 e2b = *(const f32x4*)(&el2[eb + 4]);
#pragma unroll
            for (int q = 0; q < 8; q++) {
                float e1 = (q < 4) ? e1a[q] : e1b[q - 4];
                float e2 = (q < 4) ? e2a[q] : e2b[q - 4];
                float p = fmaxf(F1 * e1, F2 * e2);
                p = ((mb >> q) & 1u) ? p : 0.f;
                if (kt == 0) f0[q] = (__bf16)p; else f1[q] = (__bf16)p;
                ps += p;
            }
        }
        lacc += ps;
    };

    stage_tile<FH>(hg + (size_t)jt0 * 64, &hbuf[0][0], tid);
    // one-time E table for this block's j range (coalesced s2 reads)
    for (int i = tid; i < NJT * 64; i += 256) {
        float s = s2[jt0 * 64 + i];
        el1[i] = EXP2(s);
        el2[i] = EXP2(0.2f * s);
    }
    PLOAD(jt0);
    __syncthreads();                              // el visible (also drains DMA 0)
    bf16x8 fc0, fc1, fn0, fn1;
    PMATH(0, fc0, fc1);                           // tile 0 fragments
    if (NJT > 1) PLOAD(jt0 + 1);

    for (int jl = 0; jl < NJT; jl++) {
        const int b = jl & 1;
        const int jt = jt0 + jl;
        // hbuf[b] DMA drained (vmcnt 0); hbuf[b^1] free to overwrite
        __syncthreads();
        if (jl + 1 < NJT)
            stage_tile<FH>(hg + (size_t)(jt + 1) * 64, &hbuf[b ^ 1][0], tid);
        // produce NEXT tile's fragments — interleaves with the MFMA cluster
        if (jl + 1 < NJT) PMATH(jl + 1, fn0, fn1);
        if (jl + 2 < NJT) PLOAD(jt + 2);
        // consume: own m-tile, ALL n-tiles (wave-local, no cross-wave sync)
        __builtin_amdgcn_s_setprio(1);
#pragma unroll
        for (int ntl = 0; ntl < NTL; ntl++) {
            int f = ntl * 16 + rl;
            int s0 = o ^ (rl & 7);                // kt=0 slot
            int s1 = (4 + o) ^ (rl & 7);          // kt=1 slot
            bf16x8 b0 = *(const bf16x8*)(&hbuf[b][(f * 8 + s0) * 8]);
            bf16x8 b1 = *(const bf16x8*)(&hbuf[b][(f * 8 + s1) * 8]);
            acc[ntl] = __builtin_amdgcn_mfma_f32_16x16x32_bf16(fc0, b0, acc[ntl], 0, 0, 0);
            acc[ntl] = __builtin_amdgcn_mfma_f32_16x16x32_bf16(fc1, b1, acc[ntl], 0, 0, 0);
        }
        __builtin_amdgcn_s_setprio(0);
        if (jl + 1 < NJT) { fc0 = fn0; fc1 = fn1; }
    }
    // ---- epilogue: cross-lane lacc reduce (deferred from loop) ----
    lacc += __shfl_xor(lacc, 16, 64);
    lacc += __shfl_xor(lacc, 32, 64);
    if (l < 16) lg[((size_t)head * JSPLIT + js) * NN + row0 + w * 16 + l] = lacc;
#pragma unroll
    for (int ntl = 0; ntl < NTL; ntl++)
#pragma unroll
        for (int r4 = 0; r4 < 4; r4++) {
            int grow = row0 + w * 16 + o * 4 + r4;
            int gcol = head * FH + ntl * 16 + rl;
            accp[((size_t)js * NN + grow) * ldo + gcol] = (__bf16)acc[ntl][r4];
        }
}

// ---------------- combine layer-2 partials + elu + log_softmax -> out ----------------
__global__ void combine2_kernel(const __bf16* __restrict__ accp, const float* __restrict__ lg,
                                float* __restrict__ out) {
    int row = (blockIdx.x * 256 + threadIdx.x) >> 6;
    int lane = threadIdx.x & 63;
    if (row >= NN) return;
    float lsum = 0.f, v = 0.f;
#pragma unroll
    for (int js = 0; js < 16; js++) {
        lsum += lg[(size_t)js * NN + row];
        v += (float)accp[((size_t)js * NN + row) * 64 + lane];
    }
    float inv = lsum > 0.f ? 1.f / lsum : 0.f;
    v *= inv;
    v = v > 0.f ? v : __expf(v) - 1.f;
    float m = v;
#pragma unroll
    for (int off = 1; off < 64; off <<= 1) m = fmaxf(m, __shfl_xor(m, off, 64));
    float ex = __expf(v - m);
    float s = ex;
#pragma unroll
    for (int off = 1; off < 64; off <<= 1) s += __shfl_xor(s, off, 64);
    out[(size_t)row * 64 + lane] = v - m - __logf(s);
}

extern "C" void kernel_launch(void* const* d_in, const int* in_sizes, int n_in,
                              void* d_out, int out_size, void* d_ws, size_t ws_size,
                              hipStream_t stream) {
    const float* X    = (const float*)d_in[0];
    const int*   adj  = (const int*)d_in[1];
    const float* W_h  = (const float*)d_in[2];
    const float* b_h  = (const float*)d_in[3];
    const float* a1_h = (const float*)d_in[4];
    const float* a2_h = (const float*)d_in[5];
    const float* ab_h = (const float*)d_in[6];
    const float* W_o  = (const float*)d_in[7];
    const float* b_o  = (const float*)d_in[8];
    const float* a1_o = (const float*)d_in[9];
    const float* a2_o = (const float*)d_in[10];
    const float* ab_o = (const float*)d_in[11];
    float* out = (float*)d_out;

    char* ws = (char*)d_ws;
    auto alloc = [&](size_t bytes) {
        char* p = ws; ws += (bytes + 255) & ~(size_t)255; return p;
    };
    unsigned long long* adj_bits = (unsigned long long*)alloc((size_t)NN * 64 * 8); // 2 MB
    __bf16* Bt1    = (__bf16*)alloc((size_t)512 * 512 * 2);     // 512 KB
    float*  biasp  = (float*)alloc(512 * 4);
    __bf16* Bt2    = (__bf16*)alloc((size_t)64 * 512 * 2);      // 64 KB
    __bf16* Xb     = (__bf16*)alloc((size_t)NN * 512 * 2);      // 4 MB
    float*  s1h    = (float*)alloc((size_t)4 * NN * 4);         // |-- contiguous,
    float*  s2h    = (float*)alloc((size_t)4 * NN * 4);         // |   zeroed by prep
    float*  s1o    = (float*)alloc((size_t)NN * 4);             // |   (160 KB)
    float*  s2o    = (float*)alloc((size_t)NN * 4);             // |
    __bf16* Htg    = (__bf16*)alloc((size_t)512 * NN * 2);      // 4 MB
    __bf16* accp1  = (__bf16*)alloc((size_t)4 * NN * 512 * 2);  // 16 MB
    float*  lg1    = (float*)alloc((size_t)16 * NN * 4);        // 256 KB
    __bf16* Ht2    = (__bf16*)alloc((size_t)64 * NN * 2);       // 512 KB
    __bf16* accp2  = (__bf16*)alloc((size_t)16 * NN * 64 * 2);  // 8 MB
    float*  lg2    = (float*)alloc((size_t)16 * NN * 4);        // 256 KB  (~36 MB)

    // 1. fused prep: adj->bits, weight prepack, X cast, s1/s2 zeroing
    prep_kernel<<<7168, 256, 0, stream>>>(adj, adj_bits, W_h, b_h, W_o,
                                          Bt1, biasp, Bt2, X, Xb, s1h);
    // 2. layer-1 GEMM fused: Htg (transposed bf16) + s1h/s2h atomics (LOG2E-scaled)
    gemm_fused_kernel<0><<<dim3(8, 64), 256, 0, stream>>>(
        Xb, Bt1, biasp, a1_h, a2_h, Htg, s1h, s2h, nullptr, nullptr, NN, 512, 512);
    // 3. attention layer 1 partials (4 heads x 4 j-splits)
    attn_kernel<128, 4><<<dim3(NN / 64, 4, 4), 256, 0, stream>>>(
        Htg, adj_bits, s1h, s2h, ab_h, accp1, lg1, 512);
    // 4. layer-2 GEMM with combine1 FUSED into the A-path (reads accp1+lg1 directly)
    gemm_fused_kernel<1><<<dim3(1, 64), 256, 0, stream>>>(
        nullptr, Bt2, b_o, a1_o, a2_o, Ht2, s1o, s2o, accp1, lg1, NN, 64, 512);
    // 5. attention layer 2 partials (16 j-splits)
    attn_kernel<64, 16><<<dim3(NN / 64, 1, 16), 256, 0, stream>>>(
        Ht2, adj_bits, s1o, s2o, ab_o, accp2, lg2, 64);
    // 6. combine + elu + log_softmax -> out
    combine2_kernel<<<(NN * 64) / 256, 256, 0, stream>>>(accp2, lg2, out);
}